// Round 4
// baseline (168.196 us; speedup 1.0000x reference)
//
#include <hip/hip_runtime.h>
#include <hip/hip_bf16.h>

#define BATCH 16384
#define MAX_ITEMS 200

// ---------------------------------------------------------------------------
// Fully fused NCF scoring. One block (256 threads = 4 waves) per user.
//
// Phase 1: wave w computes projection w (64 -> 4 dot products):
//    wave 0: gmf_user  = uemb[u][0:64]   @ W0.T + b0
//    wave 1: ncf_user  = uemb[u][64:128] @ W1.T + b1
//    wave 2: gmf_noise = noise[u][0:64]  @ W2.T + b2
//    wave 3: ncf_noise = noise[u][64:128]@ W3.T + b3
// 16 results -> LDS. Every thread then folds them (redundantly, in regs) into
//    uu[j]   = Wf[j]*gu[j] + Wf[4+j]*gn[j]                      (j=0..3)
//    base[k] = bn[k] + Wn[k][0:4].nu + Wn[k][4:8].nn            (k=0..7)
//
// Phase 2: threads 0..199 score one item each:
//    score = bf + dot(gmf_item, uu) + sum_k Wf[8+k]*relu(base[k] + Wn[k][8:12].ncf_item)
//    out   = p*rating + score
//
// ratings/ids loads are issued at kernel entry (latency hides under phase 1);
// the dependent embedding gathers are issued before the barrier.
// ---------------------------------------------------------------------------
__global__ __launch_bounds__(256) void ncf_fused(
    const float* __restrict__ ratings,
    const int*   __restrict__ ids,
    const float* __restrict__ noise,
    const float* __restrict__ uemb,
    const float* __restrict__ gmf_emb,
    const float* __restrict__ ncf_emb,
    const float* __restrict__ W0, const float* __restrict__ b0,
    const float* __restrict__ W1, const float* __restrict__ b1,
    const float* __restrict__ W2, const float* __restrict__ b2,
    const float* __restrict__ W3, const float* __restrict__ b3,
    const float* __restrict__ Wn, const float* __restrict__ bn,
    const float* __restrict__ Wf, const float* __restrict__ bf,
    const float* __restrict__ p,
    float* __restrict__ out)
{
    __shared__ float sproj[16];

    const int u    = blockIdx.x;
    const int tid  = threadIdx.x;
    const int wave = tid >> 6;
    const int lane = tid & 63;

    // ---- issue the streaming loads for phase 2 immediately ----
    const bool active = tid < MAX_ITEMS;
    const size_t idx  = (size_t)u * MAX_ITEMS + tid;
    float rating = 0.0f;
    int   id     = 0;
    if (active) {
        rating = ratings[idx];
        id     = ids[idx];
    }

    // ---- phase 1: per-wave 64->4 projection ----
    const float* Wsel;
    const float* bsel;
    const float* src;
    if      (wave == 0) { Wsel = W0; bsel = b0; src = uemb  + (size_t)u * 128;      }
    else if (wave == 1) { Wsel = W1; bsel = b1; src = uemb  + (size_t)u * 128 + 64; }
    else if (wave == 2) { Wsel = W2; bsel = b2; src = noise + (size_t)u * 128;      }
    else                { Wsel = W3; bsel = b3; src = noise + (size_t)u * 128 + 64; }

    float x = src[lane];
#pragma unroll
    for (int j = 0; j < 4; ++j) {
        float s = x * Wsel[j * 64 + lane];
#pragma unroll
        for (int m = 1; m < 64; m <<= 1)
            s += __shfl_xor(s, m, 64);
        if (lane == 0)
            sproj[wave * 4 + j] = s + bsel[j];
    }

    // ---- issue the dependent gathers before the barrier ----
    float4 gi = make_float4(0.f, 0.f, 0.f, 0.f);
    float4 ni = make_float4(0.f, 0.f, 0.f, 0.f);
    if (active) {
        gi = *reinterpret_cast<const float4*>(gmf_emb + (size_t)id * 4);
        ni = *reinterpret_cast<const float4*>(ncf_emb + (size_t)id * 4);
    }

    __syncthreads();

    // ---- fold the 16 projections into per-user constants (all threads) ----
    float pr[16];
#pragma unroll
    for (int i = 0; i < 16; ++i) pr[i] = sproj[i];
    // pr[0..3]=gmf_user, pr[4..7]=ncf_user, pr[8..11]=gmf_noise, pr[12..15]=ncf_noise

    float uu[4];
#pragma unroll
    for (int j = 0; j < 4; ++j)
        uu[j] = Wf[j] * pr[j] + Wf[4 + j] * pr[8 + j];

    float base[8];
#pragma unroll
    for (int k = 0; k < 8; ++k) {
        float t = bn[k];
#pragma unroll
        for (int i = 0; i < 4; ++i)
            t += Wn[k * 12 + i] * pr[4 + i] + Wn[k * 12 + 4 + i] * pr[12 + i];
        base[k] = t;
    }

    // ---- phase 2: score ----
    if (active) {
        float acc = bf[0]
                  + gi.x * uu[0] + gi.y * uu[1] + gi.z * uu[2] + gi.w * uu[3];
#pragma unroll
        for (int k = 0; k < 8; ++k) {
            float t = base[k]
                    + Wn[k * 12 + 8]  * ni.x
                    + Wn[k * 12 + 9]  * ni.y
                    + Wn[k * 12 + 10] * ni.z
                    + Wn[k * 12 + 11] * ni.w;
            acc += Wf[8 + k] * fmaxf(t, 0.0f);
        }
        out[idx] = p[0] * rating + acc;
    }
}

extern "C" void kernel_launch(void* const* d_in, const int* in_sizes, int n_in,
                              void* d_out, int out_size, void* d_ws, size_t ws_size,
                              hipStream_t stream) {
    const float* ratings = (const float*)d_in[0];
    const int*   ids     = (const int*)  d_in[1];
    const float* noise   = (const float*)d_in[2];
    const float* uemb    = (const float*)d_in[3];
    const float* gmf_emb = (const float*)d_in[4];
    const float* ncf_emb = (const float*)d_in[5];
    const float* W0 = (const float*)d_in[6];
    const float* b0 = (const float*)d_in[7];
    const float* W1 = (const float*)d_in[8];
    const float* b1 = (const float*)d_in[9];
    const float* W2 = (const float*)d_in[10];
    const float* b2 = (const float*)d_in[11];
    const float* W3 = (const float*)d_in[12];
    const float* b3 = (const float*)d_in[13];
    const float* Wn = (const float*)d_in[14];
    const float* bn = (const float*)d_in[15];
    const float* Wf = (const float*)d_in[16];
    const float* bf = (const float*)d_in[17];
    const float* p  = (const float*)d_in[18];
    float* out = (float*)d_out;

    ncf_fused<<<BATCH, 256, 0, stream>>>(
        ratings, ids, noise, uemb, gmf_emb, ncf_emb,
        W0, b0, W1, b1, W2, b2, W3, b3, Wn, bn, Wf, bf, p, out);
}

// Round 8
// 152.023 us; speedup vs baseline: 1.1064x; 1.1064x over previous
//
#include <hip/hip_runtime.h>
#include <hip/hip_bf16.h>

#define BATCH 16384
#define MAX_ITEMS 200
#define TOTAL (BATCH * MAX_ITEMS)
#define A_USERS 64          // users per block in kernel A
#define B_ITEMS 4           // items per thread in kernel B

// ---------------------------------------------------------------------------
// Kernel A: per-user constants, NO cross-lane ops.
// 64 users / 256-thread block; thread (u_local = tid>>2, r = tid&3) computes
// projection r for its user as a serial 64-elem dot with 16 independent
// float4 loads (ILP-hidden latency). W0..W3 staged in LDS (stride-68 rows:
// 272B = 16B-aligned, r-groups land on 2 banks -> 2-way (free) broadcast).
// Fold: 16 projections -> 12 per-user constants via LDS, threads 0..63.
//   ws[u*12 + 0..3]  = uu[j]   = Wf[j]*gu[j] + Wf[4+j]*gn[j]
//   ws[u*12 + 4..11] = base[k] = bn[k] + Wn[k][0:4].nu + Wn[k][4:8].nn
// ---------------------------------------------------------------------------
__global__ __launch_bounds__(256) void user_precompute(
    const float* __restrict__ noise,
    const float* __restrict__ uemb,
    const float* __restrict__ W0, const float* __restrict__ b0,
    const float* __restrict__ W1, const float* __restrict__ b1,
    const float* __restrict__ W2, const float* __restrict__ b2,
    const float* __restrict__ W3, const float* __restrict__ b3,
    const float* __restrict__ Wn, const float* __restrict__ bn,
    const float* __restrict__ Wf,
    float* __restrict__ ws)
{
    __shared__ float sW[16 * 68];          // [r*4+j] rows, stride 68 floats
    __shared__ float sproj[A_USERS * 17];  // [u_local] rows, stride 17 floats

    const int tid = threadIdx.x;

    // stage all four 4x64 weight matrices into LDS
    for (int k = tid; k < 1024; k += 256) {
        int row = k >> 6;                  // 0..15
        int i   = k & 63;
        int r   = row >> 2;
        int j   = row & 3;
        const float* Wr = (r == 0) ? W0 : (r == 1) ? W1 : (r == 2) ? W2 : W3;
        sW[row * 68 + i] = Wr[j * 64 + i];
    }
    __syncthreads();

    const int u_local = tid >> 2;
    const int r       = tid & 3;
    const int u       = blockIdx.x * A_USERS + u_local;

    const float* srcbase = (r < 2) ? uemb : noise;
    const float4* src = reinterpret_cast<const float4*>(
        srcbase + (size_t)u * 128 + (r & 1) * 64);

    const float4* w0p = reinterpret_cast<const float4*>(&sW[(r * 4 + 0) * 68]);
    const float4* w1p = reinterpret_cast<const float4*>(&sW[(r * 4 + 1) * 68]);
    const float4* w2p = reinterpret_cast<const float4*>(&sW[(r * 4 + 2) * 68]);
    const float4* w3p = reinterpret_cast<const float4*>(&sW[(r * 4 + 3) * 68]);

    float a0 = 0.f, a1 = 0.f, a2 = 0.f, a3 = 0.f;
#pragma unroll
    for (int i4 = 0; i4 < 16; ++i4) {
        float4 x  = src[i4];
        float4 w0 = w0p[i4];
        float4 w1 = w1p[i4];
        float4 w2 = w2p[i4];
        float4 w3 = w3p[i4];
        a0 += x.x * w0.x + x.y * w0.y + x.z * w0.z + x.w * w0.w;
        a1 += x.x * w1.x + x.y * w1.y + x.z * w1.z + x.w * w1.w;
        a2 += x.x * w2.x + x.y * w2.y + x.z * w2.z + x.w * w2.w;
        a3 += x.x * w3.x + x.y * w3.y + x.z * w3.z + x.w * w3.w;
    }
    const float* br = (r == 0) ? b0 : (r == 1) ? b1 : (r == 2) ? b2 : b3;
    sproj[u_local * 17 + r * 4 + 0] = a0 + br[0];
    sproj[u_local * 17 + r * 4 + 1] = a1 + br[1];
    sproj[u_local * 17 + r * 4 + 2] = a2 + br[2];
    sproj[u_local * 17 + r * 4 + 3] = a3 + br[3];
    __syncthreads();

    // fold: threads 0..63, one user each
    if (tid < A_USERS) {
        float pr[16];
#pragma unroll
        for (int c = 0; c < 16; ++c) pr[c] = sproj[tid * 17 + c];
        // pr[0..3]=gmf_user, [4..7]=ncf_user, [8..11]=gmf_noise, [12..15]=ncf_noise

        float* o = ws + (size_t)(blockIdx.x * A_USERS + tid) * 12;
#pragma unroll
        for (int j = 0; j < 4; ++j)
            o[j] = Wf[j] * pr[j] + Wf[4 + j] * pr[8 + j];
#pragma unroll
        for (int k = 0; k < 8; ++k) {
            float t = bn[k];
#pragma unroll
            for (int i = 0; i < 4; ++i)
                t += Wn[k * 12 + i] * pr[4 + i] + Wn[k * 12 + 4 + i] * pr[12 + i];
            o[4 + k] = t;
        }
    }
}

// ---------------------------------------------------------------------------
// Kernel B: scoring, 4 items per thread.
// float4 ratings + int4 ids (coalesced 16B/lane); 8 independent float4
// gathers in flight per thread (tables are L2/L3-resident); per-user
// constants as 3 float4 loads (48B stride is 16B-aligned). float4 store.
// 200 % 4 == 0 -> a thread's 4 items never straddle users.
// ---------------------------------------------------------------------------
__global__ __launch_bounds__(256) void score4(
    const float* __restrict__ ratings,
    const int*   __restrict__ ids,
    const float* __restrict__ gmf_emb,
    const float* __restrict__ ncf_emb,
    const float* __restrict__ Wn,
    const float* __restrict__ Wf,
    const float* __restrict__ bf,
    const float* __restrict__ p,
    const float* __restrict__ ws,
    float* __restrict__ out)
{
    __shared__ float sWn[32];  // Wn[k][8+i], k-major
    __shared__ float sWf[8];   // Wf[8+k]
    __shared__ float sBF, sP;

    const int tid = threadIdx.x;
    if (tid < 32)       sWn[tid] = Wn[(tid >> 2) * 12 + 8 + (tid & 3)];
    else if (tid < 40)  sWf[tid - 32] = Wf[8 + (tid - 32)];
    else if (tid == 40) sBF = bf[0];
    else if (tid == 41) sP  = p[0];
    __syncthreads();

    const int t = blockIdx.x * 256 + tid;          // 0 .. 819199
    const int u = t / (MAX_ITEMS / B_ITEMS);       // t / 50 -> magic mul

    float4 r4  = reinterpret_cast<const float4*>(ratings)[t];
    int4   id4 = reinterpret_cast<const int4*>(ids)[t];

    // 8 independent gathers
    float4 gi0 = *reinterpret_cast<const float4*>(gmf_emb + (size_t)id4.x * 4);
    float4 gi1 = *reinterpret_cast<const float4*>(gmf_emb + (size_t)id4.y * 4);
    float4 gi2 = *reinterpret_cast<const float4*>(gmf_emb + (size_t)id4.z * 4);
    float4 gi3 = *reinterpret_cast<const float4*>(gmf_emb + (size_t)id4.w * 4);
    float4 ni0 = *reinterpret_cast<const float4*>(ncf_emb + (size_t)id4.x * 4);
    float4 ni1 = *reinterpret_cast<const float4*>(ncf_emb + (size_t)id4.y * 4);
    float4 ni2 = *reinterpret_cast<const float4*>(ncf_emb + (size_t)id4.z * 4);
    float4 ni3 = *reinterpret_cast<const float4*>(ncf_emb + (size_t)id4.w * 4);

    // per-user constants: uu[0..3], base[0..7]
    const float4* wsu = reinterpret_cast<const float4*>(ws + (size_t)u * 12);
    float4 c0 = wsu[0];   // uu
    float4 c1 = wsu[1];   // base[0..3]
    float4 c2 = wsu[2];   // base[4..7]
    const float base[8] = {c1.x, c1.y, c1.z, c1.w, c2.x, c2.y, c2.z, c2.w};

    const float4 gis[4] = {gi0, gi1, gi2, gi3};
    const float4 nis[4] = {ni0, ni1, ni2, ni3};
    const float  rr[4]  = {r4.x, r4.y, r4.z, r4.w};
    float res[4];

#pragma unroll
    for (int e = 0; e < 4; ++e) {
        float4 gi = gis[e];
        float4 ni = nis[e];
        float acc = sBF
                  + gi.x * c0.x + gi.y * c0.y + gi.z * c0.z + gi.w * c0.w;
#pragma unroll
        for (int k = 0; k < 8; ++k) {
            float tv = base[k]
                     + sWn[k * 4 + 0] * ni.x
                     + sWn[k * 4 + 1] * ni.y
                     + sWn[k * 4 + 2] * ni.z
                     + sWn[k * 4 + 3] * ni.w;
            acc += sWf[k] * fmaxf(tv, 0.0f);
        }
        res[e] = sP * rr[e] + acc;
    }

    reinterpret_cast<float4*>(out)[t] = make_float4(res[0], res[1], res[2], res[3]);
}

extern "C" void kernel_launch(void* const* d_in, const int* in_sizes, int n_in,
                              void* d_out, int out_size, void* d_ws, size_t ws_size,
                              hipStream_t stream) {
    const float* ratings = (const float*)d_in[0];
    const int*   ids     = (const int*)  d_in[1];
    const float* noise   = (const float*)d_in[2];
    const float* uemb    = (const float*)d_in[3];
    const float* gmf_emb = (const float*)d_in[4];
    const float* ncf_emb = (const float*)d_in[5];
    const float* W0 = (const float*)d_in[6];
    const float* b0 = (const float*)d_in[7];
    const float* W1 = (const float*)d_in[8];
    const float* b1 = (const float*)d_in[9];
    const float* W2 = (const float*)d_in[10];
    const float* b2 = (const float*)d_in[11];
    const float* W3 = (const float*)d_in[12];
    const float* b3 = (const float*)d_in[13];
    const float* Wn = (const float*)d_in[14];
    const float* bn = (const float*)d_in[15];
    const float* Wf = (const float*)d_in[16];
    const float* bf = (const float*)d_in[17];
    const float* p  = (const float*)d_in[18];
    float* out = (float*)d_out;
    float* ws  = (float*)d_ws;   // 16384 * 12 floats = 768 KB

    user_precompute<<<BATCH / A_USERS, 256, 0, stream>>>(
        noise, uemb, W0, b0, W1, b1, W2, b2, W3, b3, Wn, bn, Wf, ws);

    score4<<<TOTAL / B_ITEMS / 256, 256, 0, stream>>>(
        ratings, ids, gmf_emb, ncf_emb, Wn, Wf, bf, p, ws, out);
}

// Round 9
// 141.741 us; speedup vs baseline: 1.1866x; 1.0725x over previous
//
#include <hip/hip_runtime.h>
#include <hip/hip_bf16.h>

#define BATCH 16384
#define MAX_ITEMS 200
#define TOTAL (BATCH * MAX_ITEMS)
#define NUM_ITEMS 100000
#define A_USERS 64

typedef _Float16 half8 __attribute__((ext_vector_type(8)));

// ---------------------------------------------------------------------------
// Kernel P: pack per-item embeddings into one 16B row of 8 x f16:
//   packed[i] = {gmf_emb[i][0..3], ncf_emb[i][0..3]}
// One divergent gather instead of two in the score kernel (theory: score time
// tracks divergent gather lane-request count; this halves it).
// ---------------------------------------------------------------------------
__global__ __launch_bounds__(256) void pack_items(
    const float* __restrict__ gmf_emb,
    const float* __restrict__ ncf_emb,
    half8* __restrict__ packed)
{
    int i = blockIdx.x * 256 + threadIdx.x;
    if (i >= NUM_ITEMS) return;
    float4 g = reinterpret_cast<const float4*>(gmf_emb)[i];
    float4 c = reinterpret_cast<const float4*>(ncf_emb)[i];
    half8 z;
    z[0] = (_Float16)g.x; z[1] = (_Float16)g.y;
    z[2] = (_Float16)g.z; z[3] = (_Float16)g.w;
    z[4] = (_Float16)c.x; z[5] = (_Float16)c.y;
    z[6] = (_Float16)c.z; z[7] = (_Float16)c.w;
    packed[i] = z;
}

// ---------------------------------------------------------------------------
// Kernel A: per-user constants. 64 users / 256-thread block, 256 blocks.
// All global reads fully coalesced (float4, consecutive across lanes) into
// LDS; the 64->4 dots then read LDS. No cross-lane ops.
//   consts[u*12 + 0..3]  = uu[j]   = Wf[j]*gmf_user[j] + Wf[4+j]*gmf_noise[j]
//   consts[u*12 + 4..11] = base[k] = bn[k] + Wn[k][0:4].ncf_user + Wn[k][4:8].ncf_noise
// ---------------------------------------------------------------------------
__global__ __launch_bounds__(256) void user_precompute(
    const float* __restrict__ noise,
    const float* __restrict__ uemb,
    const float* __restrict__ W0, const float* __restrict__ b0,
    const float* __restrict__ W1, const float* __restrict__ b1,
    const float* __restrict__ W2, const float* __restrict__ b2,
    const float* __restrict__ W3, const float* __restrict__ b3,
    const float* __restrict__ Wn, const float* __restrict__ bn,
    const float* __restrict__ Wf,
    float* __restrict__ consts)
{
    __shared__ float sIn[A_USERS * 260];   // [u][0:128]=uemb row, [128:256]=noise row
    __shared__ float sW[16 * 68];          // rows r*4+j, stride 68
    __shared__ float sproj[A_USERS * 17];

    const int tid = threadIdx.x;
    const int ub  = blockIdx.x * A_USERS;

    // stage weights (1024 floats)
    for (int k = tid; k < 1024; k += 256) {
        int row = k >> 6, i = k & 63;
        int r = row >> 2, j = row & 3;
        const float* Wr = (r == 0) ? W0 : (r == 1) ? W1 : (r == 2) ? W2 : W3;
        sW[row * 68 + i] = Wr[j * 64 + i];
    }

    // stage 64 users' uemb+noise rows, fully coalesced
    const float4* ue4 = reinterpret_cast<const float4*>(uemb  + (size_t)ub * 128);
    const float4* no4 = reinterpret_cast<const float4*>(noise + (size_t)ub * 128);
#pragma unroll
    for (int it = 0; it < 8; ++it) {
        int k   = it * 256 + tid;          // 0 .. 2047
        int u_l = k >> 5, seg = k & 31;
        float4 v = ue4[k];
        float4 w = no4[k];
        *reinterpret_cast<float4*>(&sIn[u_l * 260 + seg * 4])       = v;
        *reinterpret_cast<float4*>(&sIn[u_l * 260 + 128 + seg * 4]) = w;
    }
    __syncthreads();

    // 64 -> 4 dot products: thread (u_local, r) does projection r for its user
    const int u_local = tid >> 2;
    const int r       = tid & 3;
    // r=0: uemb[0:64], r=1: uemb[64:128], r=2: noise[0:64], r=3: noise[64:128]
    const float4* src = reinterpret_cast<const float4*>(&sIn[u_local * 260 + r * 64]);
    const float4* w0p = reinterpret_cast<const float4*>(&sW[(r * 4 + 0) * 68]);
    const float4* w1p = reinterpret_cast<const float4*>(&sW[(r * 4 + 1) * 68]);
    const float4* w2p = reinterpret_cast<const float4*>(&sW[(r * 4 + 2) * 68]);
    const float4* w3p = reinterpret_cast<const float4*>(&sW[(r * 4 + 3) * 68]);

    float a0 = 0.f, a1 = 0.f, a2 = 0.f, a3 = 0.f;
#pragma unroll
    for (int i4 = 0; i4 < 16; ++i4) {
        float4 x  = src[i4];
        float4 w0 = w0p[i4];
        float4 w1 = w1p[i4];
        float4 w2 = w2p[i4];
        float4 w3 = w3p[i4];
        a0 += x.x * w0.x + x.y * w0.y + x.z * w0.z + x.w * w0.w;
        a1 += x.x * w1.x + x.y * w1.y + x.z * w1.z + x.w * w1.w;
        a2 += x.x * w2.x + x.y * w2.y + x.z * w2.z + x.w * w2.w;
        a3 += x.x * w3.x + x.y * w3.y + x.z * w3.z + x.w * w3.w;
    }
    const float* br = (r == 0) ? b0 : (r == 1) ? b1 : (r == 2) ? b2 : b3;
    sproj[u_local * 17 + r * 4 + 0] = a0 + br[0];
    sproj[u_local * 17 + r * 4 + 1] = a1 + br[1];
    sproj[u_local * 17 + r * 4 + 2] = a2 + br[2];
    sproj[u_local * 17 + r * 4 + 3] = a3 + br[3];
    __syncthreads();

    // fold: threads 0..63, one user each; write 3 float4s
    if (tid < A_USERS) {
        float pr[16];
#pragma unroll
        for (int c = 0; c < 16; ++c) pr[c] = sproj[tid * 17 + c];
        // pr[0..3]=gmf_user, [4..7]=ncf_user, [8..11]=gmf_noise, [12..15]=ncf_noise

        float uu[4], base[8];
#pragma unroll
        for (int j = 0; j < 4; ++j)
            uu[j] = Wf[j] * pr[j] + Wf[4 + j] * pr[8 + j];
#pragma unroll
        for (int k = 0; k < 8; ++k) {
            float t = bn[k];
#pragma unroll
            for (int i = 0; i < 4; ++i)
                t += Wn[k * 12 + i] * pr[4 + i] + Wn[k * 12 + 4 + i] * pr[12 + i];
            base[k] = t;
        }
        float4* o = reinterpret_cast<float4*>(consts + (size_t)(ub + tid) * 12);
        o[0] = make_float4(uu[0], uu[1], uu[2], uu[3]);
        o[1] = make_float4(base[0], base[1], base[2], base[3]);
        o[2] = make_float4(base[4], base[5], base[6], base[7]);
    }
}

// ---------------------------------------------------------------------------
// Kernel B: scoring, 4 items per thread, ONE 16B gather per item.
//   score = bf + dot(gi, uu) + sum_k Wf[8+k]*relu(base[k] + Wn[k][8:12].ni)
// ---------------------------------------------------------------------------
__global__ __launch_bounds__(256) void score4(
    const float* __restrict__ ratings,
    const int*   __restrict__ ids,
    const half8* __restrict__ packed,
    const float* __restrict__ Wn,
    const float* __restrict__ Wf,
    const float* __restrict__ bf,
    const float* __restrict__ p,
    const float* __restrict__ consts,
    float* __restrict__ out)
{
    __shared__ float sWn[32];  // Wn[k][8+i], k-major
    __shared__ float sWf[8];   // Wf[8+k]
    __shared__ float sBF, sP;

    const int tid = threadIdx.x;
    if (tid < 32)       sWn[tid] = Wn[(tid >> 2) * 12 + 8 + (tid & 3)];
    else if (tid < 40)  sWf[tid - 32] = Wf[8 + (tid - 32)];
    else if (tid == 40) sBF = bf[0];
    else if (tid == 41) sP  = p[0];
    __syncthreads();

    const int t = blockIdx.x * 256 + tid;          // 0 .. 204799
    const int u = t / (MAX_ITEMS / 4);             // t / 50 -> magic mul

    float4 r4  = reinterpret_cast<const float4*>(ratings)[t];
    int4   id4 = reinterpret_cast<const int4*>(ids)[t];

    // 4 independent 16B gathers (one per item)
    half8 z0 = packed[id4.x];
    half8 z1 = packed[id4.y];
    half8 z2 = packed[id4.z];
    half8 z3 = packed[id4.w];

    // per-user constants
    const float4* cu = reinterpret_cast<const float4*>(consts + (size_t)u * 12);
    float4 c0 = cu[0];   // uu
    float4 c1 = cu[1];   // base[0..3]
    float4 c2 = cu[2];   // base[4..7]
    const float base[8] = {c1.x, c1.y, c1.z, c1.w, c2.x, c2.y, c2.z, c2.w};

    const half8 zs[4] = {z0, z1, z2, z3};
    const float rr[4] = {r4.x, r4.y, r4.z, r4.w};
    float res[4];

#pragma unroll
    for (int e = 0; e < 4; ++e) {
        half8 z = zs[e];
        float gx = (float)z[0], gy = (float)z[1], gz = (float)z[2], gw = (float)z[3];
        float nx = (float)z[4], ny = (float)z[5], nz = (float)z[6], nw = (float)z[7];
        float acc = sBF + gx * c0.x + gy * c0.y + gz * c0.z + gw * c0.w;
#pragma unroll
        for (int k = 0; k < 8; ++k) {
            float tv = base[k]
                     + sWn[k * 4 + 0] * nx
                     + sWn[k * 4 + 1] * ny
                     + sWn[k * 4 + 2] * nz
                     + sWn[k * 4 + 3] * nw;
            acc += sWf[k] * fmaxf(tv, 0.0f);
        }
        res[e] = sP * rr[e] + acc;
    }

    reinterpret_cast<float4*>(out)[t] = make_float4(res[0], res[1], res[2], res[3]);
}

extern "C" void kernel_launch(void* const* d_in, const int* in_sizes, int n_in,
                              void* d_out, int out_size, void* d_ws, size_t ws_size,
                              hipStream_t stream) {
    const float* ratings = (const float*)d_in[0];
    const int*   ids     = (const int*)  d_in[1];
    const float* noise   = (const float*)d_in[2];
    const float* uemb    = (const float*)d_in[3];
    const float* gmf_emb = (const float*)d_in[4];
    const float* ncf_emb = (const float*)d_in[5];
    const float* W0 = (const float*)d_in[6];
    const float* b0 = (const float*)d_in[7];
    const float* W1 = (const float*)d_in[8];
    const float* b1 = (const float*)d_in[9];
    const float* W2 = (const float*)d_in[10];
    const float* b2 = (const float*)d_in[11];
    const float* W3 = (const float*)d_in[12];
    const float* b3 = (const float*)d_in[13];
    const float* Wn = (const float*)d_in[14];
    const float* bn = (const float*)d_in[15];
    const float* Wf = (const float*)d_in[16];
    const float* bf = (const float*)d_in[17];
    const float* p  = (const float*)d_in[18];
    float* out = (float*)d_out;

    // ws layout: [0, 1.6MB) packed f16 item table; [2MB, 2MB+768KB) user consts
    half8* packed = (half8*)d_ws;
    float* consts = (float*)((char*)d_ws + (1u << 21));

    pack_items<<<(NUM_ITEMS + 255) / 256, 256, 0, stream>>>(gmf_emb, ncf_emb, packed);

    user_precompute<<<BATCH / A_USERS, 256, 0, stream>>>(
        noise, uemb, W0, b0, W1, b1, W2, b2, W3, b3, Wn, bn, Wf, consts);

    score4<<<TOTAL / 4 / 256, 256, 0, stream>>>(
        ratings, ids, packed, Wn, Wf, bf, p, consts, out);
}

// Round 13
// 139.720 us; speedup vs baseline: 1.2038x; 1.0145x over previous
//
#include <hip/hip_runtime.h>
#include <hip/hip_bf16.h>

#define BATCH 16384
#define MAX_ITEMS 200
#define TOTAL (BATCH * MAX_ITEMS)
#define NUM_ITEMS 100000
#define A_USERS 64
#define PREP_A_BLOCKS (BATCH / A_USERS)                    // 256
#define PACK_BLOCKS ((NUM_ITEMS + 255) / 256)              // 391

typedef _Float16 half8 __attribute__((ext_vector_type(8)));
typedef float    f32x4 __attribute__((ext_vector_type(4)));  // clang vector: OK for nontemporal builtins
typedef int      i32x4 __attribute__((ext_vector_type(4)));

// ---------------------------------------------------------------------------
// Kernel PREP (merged): blocks [0,256) do per-user constants; blocks
// [256, 256+391) pack the item tables into one 16B f16 row each:
//   packed[i] = {gmf_emb[i][0..3], ncf_emb[i][0..3]}
// ---------------------------------------------------------------------------
__global__ __launch_bounds__(256) void prep(
    const float* __restrict__ noise,
    const float* __restrict__ uemb,
    const float* __restrict__ gmf_emb,
    const float* __restrict__ ncf_emb,
    const float* __restrict__ W0, const float* __restrict__ b0,
    const float* __restrict__ W1, const float* __restrict__ b1,
    const float* __restrict__ W2, const float* __restrict__ b2,
    const float* __restrict__ W3, const float* __restrict__ b3,
    const float* __restrict__ Wn, const float* __restrict__ bn,
    const float* __restrict__ Wf,
    float* __restrict__ consts,
    half8* __restrict__ packed)
{
    const int tid = threadIdx.x;

    if (blockIdx.x >= PREP_A_BLOCKS) {
        // ---- pack path ----
        int i = (blockIdx.x - PREP_A_BLOCKS) * 256 + tid;
        if (i < NUM_ITEMS) {
            float4 g = reinterpret_cast<const float4*>(gmf_emb)[i];
            float4 c = reinterpret_cast<const float4*>(ncf_emb)[i];
            half8 z;
            z[0] = (_Float16)g.x; z[1] = (_Float16)g.y;
            z[2] = (_Float16)g.z; z[3] = (_Float16)g.w;
            z[4] = (_Float16)c.x; z[5] = (_Float16)c.y;
            z[6] = (_Float16)c.z; z[7] = (_Float16)c.w;
            packed[i] = z;
        }
        return;
    }

    // ---- per-user constants path ----
    __shared__ float sIn[A_USERS * 260];   // [u][0:128]=uemb row, [128:256]=noise row
    __shared__ float sW[16 * 68];          // rows r*4+j, stride 68
    __shared__ float sproj[A_USERS * 17];

    const int ub = blockIdx.x * A_USERS;

    for (int k = tid; k < 1024; k += 256) {
        int row = k >> 6, i = k & 63;
        int r = row >> 2, j = row & 3;
        const float* Wr = (r == 0) ? W0 : (r == 1) ? W1 : (r == 2) ? W2 : W3;
        sW[row * 68 + i] = Wr[j * 64 + i];
    }

    const float4* ue4 = reinterpret_cast<const float4*>(uemb  + (size_t)ub * 128);
    const float4* no4 = reinterpret_cast<const float4*>(noise + (size_t)ub * 128);
#pragma unroll
    for (int it = 0; it < 8; ++it) {
        int k   = it * 256 + tid;          // 0 .. 2047
        int u_l = k >> 5, seg = k & 31;
        float4 v = ue4[k];
        float4 w = no4[k];
        *reinterpret_cast<float4*>(&sIn[u_l * 260 + seg * 4])       = v;
        *reinterpret_cast<float4*>(&sIn[u_l * 260 + 128 + seg * 4]) = w;
    }
    __syncthreads();

    const int u_local = tid >> 2;
    const int r       = tid & 3;
    const float4* src = reinterpret_cast<const float4*>(&sIn[u_local * 260 + r * 64]);
    const float4* w0p = reinterpret_cast<const float4*>(&sW[(r * 4 + 0) * 68]);
    const float4* w1p = reinterpret_cast<const float4*>(&sW[(r * 4 + 1) * 68]);
    const float4* w2p = reinterpret_cast<const float4*>(&sW[(r * 4 + 2) * 68]);
    const float4* w3p = reinterpret_cast<const float4*>(&sW[(r * 4 + 3) * 68]);

    float a0 = 0.f, a1 = 0.f, a2 = 0.f, a3 = 0.f;
#pragma unroll
    for (int i4 = 0; i4 < 16; ++i4) {
        float4 x  = src[i4];
        float4 w0 = w0p[i4];
        float4 w1 = w1p[i4];
        float4 w2 = w2p[i4];
        float4 w3 = w3p[i4];
        a0 += x.x * w0.x + x.y * w0.y + x.z * w0.z + x.w * w0.w;
        a1 += x.x * w1.x + x.y * w1.y + x.z * w1.z + x.w * w1.w;
        a2 += x.x * w2.x + x.y * w2.y + x.z * w2.z + x.w * w2.w;
        a3 += x.x * w3.x + x.y * w3.y + x.z * w3.z + x.w * w3.w;
    }
    const float* br = (r == 0) ? b0 : (r == 1) ? b1 : (r == 2) ? b2 : b3;
    sproj[u_local * 17 + r * 4 + 0] = a0 + br[0];
    sproj[u_local * 17 + r * 4 + 1] = a1 + br[1];
    sproj[u_local * 17 + r * 4 + 2] = a2 + br[2];
    sproj[u_local * 17 + r * 4 + 3] = a3 + br[3];
    __syncthreads();

    if (tid < A_USERS) {
        float pr[16];
#pragma unroll
        for (int c = 0; c < 16; ++c) pr[c] = sproj[tid * 17 + c];
        // pr[0..3]=gmf_user, [4..7]=ncf_user, [8..11]=gmf_noise, [12..15]=ncf_noise

        float uu[4], base[8];
#pragma unroll
        for (int j = 0; j < 4; ++j)
            uu[j] = Wf[j] * pr[j] + Wf[4 + j] * pr[8 + j];
#pragma unroll
        for (int k = 0; k < 8; ++k) {
            float t = bn[k];
#pragma unroll
            for (int i = 0; i < 4; ++i)
                t += Wn[k * 12 + i] * pr[4 + i] + Wn[k * 12 + 4 + i] * pr[12 + i];
            base[k] = t;
        }
        float4* o = reinterpret_cast<float4*>(consts + (size_t)(ub + tid) * 12);
        o[0] = make_float4(uu[0], uu[1], uu[2], uu[3]);
        o[1] = make_float4(base[0], base[1], base[2], base[3]);
        o[2] = make_float4(base[4], base[5], base[6], base[7]);
    }
}

// ---------------------------------------------------------------------------
// Kernel B: scoring, 4 items per thread, ONE 16B gather per item.
// Streaming traffic (ratings, ids, out) is NON-TEMPORAL (nt flag, early
// evict) so the 1.6MB packed table stays resident in each XCD's 4MB L2.
// ---------------------------------------------------------------------------
__global__ __launch_bounds__(256) void score4(
    const float* __restrict__ ratings,
    const int*   __restrict__ ids,
    const half8* __restrict__ packed,
    const float* __restrict__ Wn,
    const float* __restrict__ Wf,
    const float* __restrict__ bf,
    const float* __restrict__ p,
    const float* __restrict__ consts,
    float* __restrict__ out)
{
    __shared__ float sWn[32];  // Wn[k][8+i], k-major
    __shared__ float sWf[8];   // Wf[8+k]
    __shared__ float sBF, sP;

    const int tid = threadIdx.x;
    if (tid < 32)       sWn[tid] = Wn[(tid >> 2) * 12 + 8 + (tid & 3)];
    else if (tid < 40)  sWf[tid - 32] = Wf[8 + (tid - 32)];
    else if (tid == 40) sBF = bf[0];
    else if (tid == 41) sP  = p[0];
    __syncthreads();

    const int t = blockIdx.x * 256 + tid;          // 0 .. 204799
    const int u = t / (MAX_ITEMS / 4);             // t / 50 -> magic mul

    f32x4 r4  = __builtin_nontemporal_load(reinterpret_cast<const f32x4*>(ratings) + t);
    i32x4 id4 = __builtin_nontemporal_load(reinterpret_cast<const i32x4*>(ids) + t);

    // 4 independent 16B gathers (one per item) — normal (cached) loads
    half8 z0 = packed[id4.x];
    half8 z1 = packed[id4.y];
    half8 z2 = packed[id4.z];
    half8 z3 = packed[id4.w];

    const float4* cu = reinterpret_cast<const float4*>(consts + (size_t)u * 12);
    float4 c0 = cu[0];   // uu
    float4 c1 = cu[1];   // base[0..3]
    float4 c2 = cu[2];   // base[4..7]
    const float base[8] = {c1.x, c1.y, c1.z, c1.w, c2.x, c2.y, c2.z, c2.w};

    const half8 zs[4] = {z0, z1, z2, z3};
    const float rr[4] = {r4.x, r4.y, r4.z, r4.w};
    float res[4];

#pragma unroll
    for (int e = 0; e < 4; ++e) {
        half8 z = zs[e];
        float gx = (float)z[0], gy = (float)z[1], gz = (float)z[2], gw = (float)z[3];
        float nx = (float)z[4], ny = (float)z[5], nz = (float)z[6], nw = (float)z[7];
        float acc = sBF + gx * c0.x + gy * c0.y + gz * c0.z + gw * c0.w;
#pragma unroll
        for (int k = 0; k < 8; ++k) {
            float tv = base[k]
                     + sWn[k * 4 + 0] * nx
                     + sWn[k * 4 + 1] * ny
                     + sWn[k * 4 + 2] * nz
                     + sWn[k * 4 + 3] * nw;
            acc += sWf[k] * fmaxf(tv, 0.0f);
        }
        res[e] = sP * rr[e] + acc;
    }

    f32x4 o4;
    o4.x = res[0]; o4.y = res[1]; o4.z = res[2]; o4.w = res[3];
    __builtin_nontemporal_store(o4, reinterpret_cast<f32x4*>(out) + t);
}

extern "C" void kernel_launch(void* const* d_in, const int* in_sizes, int n_in,
                              void* d_out, int out_size, void* d_ws, size_t ws_size,
                              hipStream_t stream) {
    const float* ratings = (const float*)d_in[0];
    const int*   ids     = (const int*)  d_in[1];
    const float* noise   = (const float*)d_in[2];
    const float* uemb    = (const float*)d_in[3];
    const float* gmf_emb = (const float*)d_in[4];
    const float* ncf_emb = (const float*)d_in[5];
    const float* W0 = (const float*)d_in[6];
    const float* b0 = (const float*)d_in[7];
    const float* W1 = (const float*)d_in[8];
    const float* b1 = (const float*)d_in[9];
    const float* W2 = (const float*)d_in[10];
    const float* b2 = (const float*)d_in[11];
    const float* W3 = (const float*)d_in[12];
    const float* b3 = (const float*)d_in[13];
    const float* Wn = (const float*)d_in[14];
    const float* bn = (const float*)d_in[15];
    const float* Wf = (const float*)d_in[16];
    const float* bf = (const float*)d_in[17];
    const float* p  = (const float*)d_in[18];
    float* out = (float*)d_out;

    // ws layout: [0, 1.6MB) packed f16 item table; [2MB, 2MB+768KB) user consts
    half8* packed = (half8*)d_ws;
    float* consts = (float*)((char*)d_ws + (1u << 21));

    prep<<<PREP_A_BLOCKS + PACK_BLOCKS, 256, 0, stream>>>(
        noise, uemb, gmf_emb, ncf_emb,
        W0, b0, W1, b1, W2, b2, W3, b3, Wn, bn, Wf, consts, packed);

    score4<<<TOTAL / 4 / 256, 256, 0, stream>>>(
        ratings, ids, packed, Wn, Wf, bf, p, consts, out);
}